// Round 4
// baseline (207.717 us; speedup 1.0000x reference)
//
#include <hip/hip_runtime.h>
#include <math.h>

#define BB 32
#define HH 56
#define WW 56
#define IMG_PIX (HH * WW)          // 3136
#define TILE_H 4
#define TILE_W 14
#define HALO_H (TILE_H + 6)        // 10
#define HALO_W (TILE_W + 6)        // 20
#define NSLOT  (HALO_H * HALO_W)   // 200 halo slots
#define OWNED  (TILE_H * TILE_W)   // 56 owned pixels
#define TILES_PER_IMG ((HH / TILE_H) * (WW / TILE_W))  // 14*4 = 56
#define NBLK (BB * TILES_PER_IMG)  // 1792 = exactly 7 blocks/CU

typedef float vfloat4 __attribute__((ext_vector_type(4)));

// One block = one 4x14 tile of one image. No inter-block dependencies:
// the block pools its own 10x20 halo from x (redundant reads hit L2/L3),
// convolves in LDS, then scales its owned pixels (x tile is L1/L2-warm
// from the pooling pass). Out is written non-temporally (never re-read).
__global__ __launch_bounds__(256) void fused_kernel(
    const float* __restrict__ x,
    const float* __restrict__ cw,     // [7,7,2,1] HWIO
    const float* __restrict__ cb,     // [1]
    float* __restrict__ out) {
    __shared__ float2 halo[NSLOT];    // (avg, max) per halo pixel
    __shared__ float  attn_s[OWNED];

    const int bi   = blockIdx.x;
    const int b    = bi / TILES_PER_IMG;
    const int tile = bi % TILES_PER_IMG;
    const int h0   = (tile / (WW / TILE_W)) * TILE_H;   // tile/4 * 4
    const int w0   = (tile % (WW / TILE_W)) * TILE_W;   // tile%4 * 14
    const int t    = threadIdx.x;
    const int wv   = t >> 6;
    const int lane = t & 63;
    const int g    = lane >> 3;       // pixel slot within group-of-8 lanes
    const int c    = lane & 7;        // channel chunk (32 channels each)

    const vfloat4* x4 = (const vfloat4*)x;
    const size_t img_base = (size_t)b * IMG_PIX;

    // ---- Phase 1: pool the halo. 32 pixel-slots per iteration (4 waves x 8
    // groups); each 8-lane group reduces one pixel's 256 channels: 32 ch
    // accumulated in-register per lane, then a 3-stage shfl_xor butterfly.
#pragma unroll
    for (int it = 0; it < 7; ++it) {
        const int k = it * 32 + wv * 8 + g;
        if (k < NSLOT) {
            const int lh = k / HALO_W, lw = k % HALO_W;
            const int ih = h0 + lh - 3, iw = w0 + lw - 3;
            if (ih >= 0 && ih < HH && iw >= 0 && iw < WW) {
                const vfloat4* p4 = x4 + (img_base + ih * WW + iw) * 64 + c;
                vfloat4 v[8];
#pragma unroll
                for (int j = 0; j < 8; ++j) v[j] = p4[j * 8];
                vfloat4 sv = v[0], mv = v[0];
#pragma unroll
                for (int j = 1; j < 8; ++j) {
                    sv += v[j];
                    mv.x = fmaxf(mv.x, v[j].x); mv.y = fmaxf(mv.y, v[j].y);
                    mv.z = fmaxf(mv.z, v[j].z); mv.w = fmaxf(mv.w, v[j].w);
                }
                float s = (sv.x + sv.y) + (sv.z + sv.w);
                float m = fmaxf(fmaxf(mv.x, mv.y), fmaxf(mv.z, mv.w));
#pragma unroll
                for (int mask = 4; mask > 0; mask >>= 1) {
                    s += __shfl_xor(s, mask, 64);
                    m = fmaxf(m, __shfl_xor(m, mask, 64));
                }
                if (c == 0) halo[k] = make_float2(s * (1.0f / 256.0f), m);
            }
        }
    }
    __syncthreads();

    // ---- Phase 2: 7x7 SAME conv (2->1) + bias + sigmoid on owned pixels.
    // Tiny: 56 threads x 98 FMAs, all LDS-fed.
    if (t < OWNED) {
        const int r  = t / TILE_W, cc = t % TILE_W;
        const int h = h0 + r, w = w0 + cc;
        float acc = cb[0];
#pragma unroll
        for (int dh = 0; dh < 7; ++dh) {
            const int ih = h + dh - 3;
            if (ih < 0 || ih >= HH) continue;
#pragma unroll
            for (int dw = 0; dw < 7; ++dw) {
                const int iw = w + dw - 3;
                if (iw < 0 || iw >= WW) continue;
                const float2 pv = halo[(r + dh) * HALO_W + (cc + dw)];
                const float* kk = cw + (dh * 7 + dw) * 2;
                acc = fmaf(pv.x, kk[0], fmaf(pv.y, kk[1], acc));
            }
        }
        attn_s[t] = 1.0f / (1.0f + expf(-acc));
    }
    __syncthreads();

    // ---- Phase 3: out = x * attn. Wave wv streams row h0+wv (14 pixels =
    // 14 KB contiguous); x is L1/L2-warm from phase 1. NT stores for out.
    {
        const size_t rowbase = (img_base + (size_t)(h0 + wv) * WW + w0) * 64;
        vfloat4* o4 = (vfloat4*)out;
#pragma unroll
        for (int j = 0; j < TILE_W; ++j) {
            const float a = attn_s[wv * TILE_W + j];
            const size_t gi = rowbase + j * 64 + lane;
            vfloat4 v = x4[gi];
            v.x *= a; v.y *= a; v.z *= a; v.w *= a;
            __builtin_nontemporal_store(v, (vfloat4*)&o4[gi]);
        }
    }
}

extern "C" void kernel_launch(void* const* d_in, const int* in_sizes, int n_in,
                              void* d_out, int out_size, void* d_ws, size_t ws_size,
                              hipStream_t stream) {
    const float* x  = (const float*)d_in[0];
    const float* cw = (const float*)d_in[1];
    const float* cb = (const float*)d_in[2];
    float* out = (float*)d_out;
    fused_kernel<<<NBLK, 256, 0, stream>>>(x, cw, cb, out);
}